// Round 4
// baseline (412.698 us; speedup 1.0000x reference)
//
#include <hip/hip_runtime.h>
#include <cstddef>

namespace {
constexpr int B = 2;
constexpr int C = 64;
constexpr int N = 6400;             // h*w
constexpr int NT = N / 64;          // 100 tiles of 64
constexpr int MSPLIT = 5;           // m-range split: 1000 blocks, 20 iters each
constexpr int MT_PER = NT / MSPLIT; // 20
constexpr float EPS = 1e-5f;
constexpr int LS = 68;              // fp32 LDS row stride (pad)
constexpr int LSB = 72;             // bf16 LDS row stride (pad, 16B-aligned rows)
}

typedef __attribute__((ext_vector_type(8))) short short8;     // 8 bf16 = 4 VGPR (MFMA A/B frag)
typedef __attribute__((ext_vector_type(4))) float f32x4;      // MFMA C/D frag
typedef __attribute__((ext_vector_type(4))) unsigned short us4v;
typedef __attribute__((ext_vector_type(8))) unsigned short us8v;

__device__ inline unsigned short f2bf(float f) {  // RNE float->bf16
  unsigned int u = __float_as_uint(f);
  u += 0x7fffu + ((u >> 16) & 1u);
  return (unsigned short)(u >> 16);
}

// One pass over x: produce xT[b][n][c] (bf16) and gxT[b][i][m] = (g_w.x + g_b) (bf16).
// Also zeroes the 32-float stats accumulator (block 0) for this iteration.
__global__ __launch_bounds__(256) void xprep_kernel(
    const float* __restrict__ x, const float* __restrict__ g_w,
    const float* __restrict__ g_b, unsigned short* __restrict__ xT,
    unsigned short* __restrict__ gxT, float* __restrict__ stats_acc) {
  __shared__ float xs[64 * LS];   // [c][m]
  __shared__ float gwt[64 * LS];  // [c][i]
  const int b = blockIdx.x / NT;
  const int n0 = (blockIdx.x % NT) * 64;
  const int tid = threadIdx.x;
  if (blockIdx.x == 0 && tid < 32) stats_acc[tid] = 0.f;
  const int col = tid & 63, row4 = tid >> 6;
  const float* xb = x + (size_t)b * C * N;
#pragma unroll
  for (int it = 0; it < 16; ++it) {
    int r = row4 + it * 4;
    xs[r * LS + col] = xb[(size_t)r * N + n0 + col];
    gwt[col * LS + r] = g_w[r * 64 + col];  // gwt[c][i] = g_w[i][c]
  }
  __syncthreads();

  // gxT tile: rows i, cols m
  {
    const int ty = tid >> 4, tx = tid & 15;  // ty: i-group, tx: m-group
    float acc[4][4];
#pragma unroll
    for (int a = 0; a < 4; ++a) {
      float gbv = g_b[ty * 4 + a];
      acc[a][0] = gbv; acc[a][1] = gbv; acc[a][2] = gbv; acc[a][3] = gbv;
    }
#pragma unroll 8
    for (int c = 0; c < 64; ++c) {
      const f32x4 a4 = *(const f32x4*)&gwt[c * LS + ty * 4];  // i
      const f32x4 b4 = *(const f32x4*)&xs[c * LS + tx * 4];   // m
#pragma unroll
      for (int a = 0; a < 4; ++a) {
        acc[a][0] += a4[a] * b4[0]; acc[a][1] += a4[a] * b4[1];
        acc[a][2] += a4[a] * b4[2]; acc[a][3] += a4[a] * b4[3];
      }
    }
    unsigned short* gxTb = gxT + (size_t)b * 64 * N;
#pragma unroll
    for (int a = 0; a < 4; ++a) {
      us4v v;
      v[0] = f2bf(acc[a][0]); v[1] = f2bf(acc[a][1]);
      v[2] = f2bf(acc[a][2]); v[3] = f2bf(acc[a][3]);
      *(us4v*)&gxTb[(size_t)(ty * 4 + a) * N + n0 + tx * 4] = v;
    }
  }

  // xT tile: rows n (spatial), cols c — transpose out of xs
  {
    const int nloc = tid >> 2, cs = (tid & 3) * 16;
    us8v u0, u1;
#pragma unroll
    for (int j = 0; j < 8; ++j) u0[j] = f2bf(xs[(cs + j) * LS + nloc]);
#pragma unroll
    for (int j = 0; j < 8; ++j) u1[j] = f2bf(xs[(cs + 8 + j) * LS + nloc]);
    unsigned short* xTb = xT + (size_t)b * N * 64;
    *(us8v*)&xTb[(size_t)(n0 + nloc) * 64 + cs] = u0;
    *(us8v*)&xTb[(size_t)(n0 + nloc) * 64 + cs + 8] = u1;
  }
}

// v5 relation: identical loop to v4 (proven best) + NON-TEMPORAL score stores
// (score is write-once/never-read: stop evicting xT/gxT from L2 with 328 MB of
// streaming store allocations).
__global__ __launch_bounds__(256, 4) void relation_main(
    const unsigned short* __restrict__ xT, const unsigned short* __restrict__ gxT,
    float* __restrict__ score, float* __restrict__ emb_p) {
  __shared__ alignas(16) unsigned short xmT[64 * LSB];  // [m][c]
  __shared__ alignas(16) unsigned short gxt[64 * LSB];  // [i][m]
  __shared__ alignas(16) unsigned short sc[64 * LSB];   // [n][m], wave-private bands

  const int tid = threadIdx.x;
  const int w = tid >> 6, lane = tid & 63;
  const int l15 = lane & 15, quad = lane >> 4;

  const int bIdx = blockIdx.x / (NT * MSPLIT);
  const int rest = blockIdx.x % (NT * MSPLIT);
  const int nt = rest / MSPLIT;
  const int ms = rest % MSPLIT;
  const int n0 = nt * 64;
  const int nw = n0 + 16 * w;  // this wave's first n-row

  const unsigned short* xTb = xT + (size_t)bIdx * N * 64;
  const unsigned short* gxTb = gxT + (size_t)bIdx * 64 * N;
  float* scoreb = score + (size_t)bIdx * N * N;

  // loop-invariant B-operand frags (Xn, this wave's 16 n-rows), direct from global
  short8 bn0 = *(const short8*)&xTb[(size_t)(nw + l15) * 64 + quad * 8];
  short8 bn1 = *(const short8*)&xTb[(size_t)(nw + l15) * 64 + 32 + quad * 8];

  const int srow = tid >> 3, sco = (tid & 7) * 8;  // staging row/col (rows srow, srow+32)

  // prefetch m-tile 0 into registers
  const int mbase = ms * MT_PER * 64;
  us8v xm0 = *(const us8v*)&xTb[(size_t)(mbase + srow) * 64 + sco];
  us8v xm1 = *(const us8v*)&xTb[(size_t)(mbase + srow + 32) * 64 + sco];
  us8v gx0 = *(const us8v*)&gxTb[(size_t)srow * N + mbase + sco];
  us8v gx1 = *(const us8v*)&gxTb[(size_t)(srow + 32) * N + mbase + sco];

  f32x4 e[4];  // emb acc: D[i][n], [isub]; lane: col n = l15, rows i = 16*is+quad*4+r
  const f32x4 zero = {0.f, 0.f, 0.f, 0.f};
#pragma unroll
  for (int is = 0; is < 4; ++is) e[is] = zero;

  for (int j = 0; j < MT_PER; ++j) {
    const int mj = (ms * MT_PER + j) * 64;

    // WAR boundary: own LDS reads drained, then all waves aligned. No vmcnt drain.
    asm volatile("s_waitcnt lgkmcnt(0)" ::: "memory");
    __builtin_amdgcn_s_barrier();
    *(us8v*)&xmT[srow * LSB + sco] = xm0;
    *(us8v*)&xmT[(srow + 32) * LSB + sco] = xm1;
    *(us8v*)&gxt[srow * LSB + sco] = gx0;
    *(us8v*)&gxt[(srow + 32) * LSB + sco] = gx1;
    // RAW boundary: staging writes landed, then aligned; reads below stay below.
    asm volatile("s_waitcnt lgkmcnt(0)" ::: "memory");
    __builtin_amdgcn_s_barrier();
    __builtin_amdgcn_sched_barrier(0);

    if (j + 1 < MT_PER) {  // prefetch next tile: drains under this iter's compute
      const int m1 = mj + 64;
      xm0 = *(const us8v*)&xTb[(size_t)(m1 + srow) * 64 + sco];
      xm1 = *(const us8v*)&xTb[(size_t)(m1 + srow + 32) * 64 + sco];
      gx0 = *(const us8v*)&gxTb[(size_t)srow * N + m1 + sco];
      gx1 = *(const us8v*)&gxTb[(size_t)(srow + 32) * N + m1 + sco];
    }

    // aff = mfma(Xm, Xn): D[m][n]; sigmoid; fp32 score (nt dwordx4); bf16 P -> sc.
#pragma unroll
    for (int msub = 0; msub < 4; ++msub) {
      short8 am0 = *(const short8*)&xmT[(16 * msub + l15) * LSB + quad * 8];
      short8 am1 = *(const short8*)&xmT[(16 * msub + l15) * LSB + 32 + quad * 8];
      f32x4 d = __builtin_amdgcn_mfma_f32_16x16x32_bf16(am0, bn0, zero, 0, 0, 0);
      d = __builtin_amdgcn_mfma_f32_16x16x32_bf16(am1, bn1, d, 0, 0, 0);
      f32x4 sg; us4v sb;
#pragma unroll
      for (int r = 0; r < 4; ++r) {
        float t = __builtin_amdgcn_exp2f(-1.442695041f * d[r]);
        sg[r] = __builtin_amdgcn_rcpf(1.f + t);
        sb[r] = f2bf(sg[r]);
      }
      __builtin_nontemporal_store(
          sg, (f32x4*)&scoreb[(size_t)(nw + l15) * N + mj + 16 * msub + quad * 4]);
      *(us4v*)&sc[(16 * w + l15) * LSB + 16 * msub + quad * 4] = sb;
    }

    // emb += mfma(G, P): D[i][n]. P from wave-private sc band (same-wave RAW:
    // compiler inserts lgkmcnt). G from staged LDS.
    short8 p0 = *(const short8*)&sc[(16 * w + l15) * LSB + quad * 8];
    short8 p1 = *(const short8*)&sc[(16 * w + l15) * LSB + 32 + quad * 8];
#pragma unroll
    for (int is = 0; is < 4; ++is) {
      short8 g0 = *(const short8*)&gxt[(16 * is + l15) * LSB + quad * 8];
      short8 g1 = *(const short8*)&gxt[(16 * is + l15) * LSB + 32 + quad * 8];
      e[is] = __builtin_amdgcn_mfma_f32_16x16x32_bf16(g0, p0, e[is], 0, 0, 0);
      e[is] = __builtin_amdgcn_mfma_f32_16x16x32_bf16(g1, p1, e[is], 0, 0, 0);
    }
  }

  // emb partial store (fp32, dwordx4): emb_p[ms][b][n][i]
  float* ep = emb_p + ((size_t)ms * B + bIdx) * (size_t)N * 64;
#pragma unroll
  for (int is = 0; is < 4; ++is)
    *(f32x4*)&ep[(size_t)(nw + l15) * 64 + 16 * is + quad * 4] = e[is];
}

// y[b,o,n] = sum_i w_w[o,i] * emb[b,n,i] + w_b[o]; emb = sum of MSPLIT partials.
// v5: fused GroupNorm partial stats. Each thread's 16 acc values all belong to
// group g = tid>>5 (o = 4*(tid>>4)+a spans one group per thread). 32-lane
// shuffle reduce -> 2 atomicAdds per half-wave into stats_acc[(b*8+g)*2 +{0,1}].
__global__ __launch_bounds__(256) void y_kernel(
    const float* __restrict__ emb_p, const float* __restrict__ w_w,
    const float* __restrict__ w_b, float* __restrict__ y,
    float* __restrict__ stats_acc) {
  __shared__ float embT[64 * LS];  // [i][n]
  __shared__ float wt[64 * LS];    // [i][o]
  const int b = blockIdx.x / NT;
  const int n0 = (blockIdx.x % NT) * 64;
  const int tid = threadIdx.x;
  const int col = tid & 63, row4 = tid >> 6;
  const int ty = tid >> 4, tx = tid & 15;
#pragma unroll
  for (int it = 0; it < 16; ++it) {
    int r = row4 + it * 4;
    wt[col * LS + r] = w_w[r * 64 + col];
    float v = 0.f;
#pragma unroll
    for (int msv = 0; msv < MSPLIT; ++msv)
      v += emb_p[((size_t)msv * B + b) * N * C + (size_t)(n0 + r) * C + col];
    embT[col * LS + r] = v;
  }
  __syncthreads();
  float acc[4][4];
#pragma unroll
  for (int a = 0; a < 4; ++a) {
    float wbv = w_b[ty * 4 + a];
    acc[a][0] = wbv; acc[a][1] = wbv; acc[a][2] = wbv; acc[a][3] = wbv;
  }
#pragma unroll 8
  for (int i = 0; i < 64; ++i) {
    const f32x4 w4 = *(const f32x4*)&wt[i * LS + ty * 4];
    const f32x4 e4 = *(const f32x4*)&embT[i * LS + tx * 4];
#pragma unroll
    for (int a = 0; a < 4; ++a) {
      acc[a][0] += w4[a] * e4[0]; acc[a][1] += w4[a] * e4[1];
      acc[a][2] += w4[a] * e4[2]; acc[a][3] += w4[a] * e4[3];
    }
  }
  float* yb = y + (size_t)b * C * N;
  float s = 0.f, q = 0.f;
#pragma unroll
  for (int a = 0; a < 4; ++a) {
    f32x4 v = {acc[a][0], acc[a][1], acc[a][2], acc[a][3]};
    *(f32x4*)&yb[(size_t)(ty * 4 + a) * N + n0 + tx * 4] = v;
    s += v[0] + v[1] + v[2] + v[3];
    q += v[0] * v[0] + v[1] * v[1] + v[2] * v[2] + v[3] * v[3];
  }
#pragma unroll
  for (int off = 16; off > 0; off >>= 1) {
    s += __shfl_down(s, off, 32);
    q += __shfl_down(q, off, 32);
  }
  if ((tid & 31) == 0) {
    const int g = tid >> 5;  // group of this half-wave's 8 channels
    atomicAdd(&stats_acc[(b * 8 + g) * 2 + 0], s);
    atomicAdd(&stats_acc[(b * 8 + g) * 2 + 1], q);
  }
}

// v5: finalize folded in — mean/rstd from the (S,Q) accumulators (L2-hot, 2
// broadcast loads per thread).
__global__ __launch_bounds__(256) void norm_kernel(
    const float* __restrict__ y, const float* __restrict__ stats_acc,
    const float* __restrict__ gn_w, const float* __restrict__ gn_b,
    float* __restrict__ out) {
  const int idx = blockIdx.x * 256 + threadIdx.x;
  const int e0 = idx * 4;
  const int b = e0 / (C * N);
  const int c = (e0 / N) & 63;
  const int g = c >> 3;
  const float S = stats_acc[(b * 8 + g) * 2 + 0];
  const float Q = stats_acc[(b * 8 + g) * 2 + 1];
  const float inv = 1.f / (float)(8 * N);
  const float mean = S * inv;
  const float var = Q * inv - mean * mean;
  const float rstd = rsqrtf(var + EPS);
  const float w = gn_w[c] * rstd;
  const float bb = gn_b[c] - mean * w;
  f32x4 v = *(const f32x4*)&y[e0];
  v[0] = v[0] * w + bb; v[1] = v[1] * w + bb;
  v[2] = v[2] * w + bb; v[3] = v[3] * w + bb;
  *(f32x4*)&out[e0] = v;
}

extern "C" void kernel_launch(void* const* d_in, const int* in_sizes, int n_in,
                              void* d_out, int out_size, void* d_ws, size_t ws_size,
                              hipStream_t stream) {
  const float* x    = (const float*)d_in[0];
  const float* g_w  = (const float*)d_in[1];
  const float* g_b  = (const float*)d_in[2];
  const float* w_w  = (const float*)d_in[3];
  const float* w_b  = (const float*)d_in[4];
  const float* gn_w = (const float*)d_in[5];
  const float* gn_b = (const float*)d_in[6];
  (void)in_sizes; (void)n_in; (void)out_size; (void)ws_size;

  float* out   = (float*)d_out;
  float* score = out + (size_t)B * C * N;

  float* ws    = (float*)d_ws;
  float* emb_p = ws;                                       // MSPLIT*B*N*C fp32
  float* y     = emb_p + (size_t)MSPLIT * B * N * C;       // B*C*N fp32
  float* stats = y + (size_t)B * C * N;                    // 32 fp32 (S,Q accum)
  unsigned short* xT  = (unsigned short*)(stats + 32);     // B*N*64 bf16
  unsigned short* gxT = xT + (size_t)B * N * 64;           // B*64*N bf16

  hipLaunchKernelGGL(xprep_kernel, dim3(B * NT), dim3(256), 0, stream,
                     x, g_w, g_b, xT, gxT, stats);
  hipLaunchKernelGGL(relation_main, dim3(B * NT * MSPLIT), dim3(256), 0, stream,
                     xT, gxT, score, emb_p);
  hipLaunchKernelGGL(y_kernel, dim3(B * NT), dim3(256), 0, stream,
                     emb_p, w_w, w_b, y, stats);
  hipLaunchKernelGGL(norm_kernel, dim3((B * C * N) / 1024), dim3(256), 0, stream,
                     y, stats, gn_w, gn_b, out);
}

// Round 5
// 387.448 us; speedup vs baseline: 1.0652x; 1.0652x over previous
//
#include <hip/hip_runtime.h>
#include <cstddef>

namespace {
constexpr int B = 2;
constexpr int C = 64;
constexpr int N = 6400;             // h*w
constexpr int NT = N / 64;          // 100 tiles of 64
constexpr int MSPLIT = 5;           // m-range split: 1000 blocks, 20 iters each
constexpr int MT_PER = NT / MSPLIT; // 20
constexpr float EPS = 1e-5f;
constexpr int LS = 68;              // fp32 LDS row stride (pad)
constexpr int LSB = 72;             // bf16 LDS row stride (pad, 16B-aligned rows)
}

typedef __attribute__((ext_vector_type(8))) short short8;     // 8 bf16 = 4 VGPR (MFMA A/B frag)
typedef __attribute__((ext_vector_type(4))) float f32x4;      // MFMA C/D frag
typedef __attribute__((ext_vector_type(4))) unsigned short us4v;
typedef __attribute__((ext_vector_type(8))) unsigned short us8v;

__device__ inline unsigned short f2bf(float f) {  // RNE float->bf16
  unsigned int u = __float_as_uint(f);
  u += 0x7fffu + ((u >> 16) & 1u);
  return (unsigned short)(u >> 16);
}

// One pass over x: produce xT[b][n][c] (bf16) and gxT[b][i][m] = (g_w.x + g_b) (bf16).
// Also zeroes the 32-float stats accumulator (block 0) for this iteration.
__global__ __launch_bounds__(256) void xprep_kernel(
    const float* __restrict__ x, const float* __restrict__ g_w,
    const float* __restrict__ g_b, unsigned short* __restrict__ xT,
    unsigned short* __restrict__ gxT, float* __restrict__ stats_acc) {
  __shared__ float xs[64 * LS];   // [c][m]
  __shared__ float gwt[64 * LS];  // [c][i]
  const int b = blockIdx.x / NT;
  const int n0 = (blockIdx.x % NT) * 64;
  const int tid = threadIdx.x;
  if (blockIdx.x == 0 && tid < 32) stats_acc[tid] = 0.f;
  const int col = tid & 63, row4 = tid >> 6;
  const float* xb = x + (size_t)b * C * N;
#pragma unroll
  for (int it = 0; it < 16; ++it) {
    int r = row4 + it * 4;
    xs[r * LS + col] = xb[(size_t)r * N + n0 + col];
    gwt[col * LS + r] = g_w[r * 64 + col];  // gwt[c][i] = g_w[i][c]
  }
  __syncthreads();

  // gxT tile: rows i, cols m
  {
    const int ty = tid >> 4, tx = tid & 15;  // ty: i-group, tx: m-group
    float acc[4][4];
#pragma unroll
    for (int a = 0; a < 4; ++a) {
      float gbv = g_b[ty * 4 + a];
      acc[a][0] = gbv; acc[a][1] = gbv; acc[a][2] = gbv; acc[a][3] = gbv;
    }
#pragma unroll 8
    for (int c = 0; c < 64; ++c) {
      const f32x4 a4 = *(const f32x4*)&gwt[c * LS + ty * 4];  // i
      const f32x4 b4 = *(const f32x4*)&xs[c * LS + tx * 4];   // m
#pragma unroll
      for (int a = 0; a < 4; ++a) {
        acc[a][0] += a4[a] * b4[0]; acc[a][1] += a4[a] * b4[1];
        acc[a][2] += a4[a] * b4[2]; acc[a][3] += a4[a] * b4[3];
      }
    }
    unsigned short* gxTb = gxT + (size_t)b * 64 * N;
#pragma unroll
    for (int a = 0; a < 4; ++a) {
      us4v v;
      v[0] = f2bf(acc[a][0]); v[1] = f2bf(acc[a][1]);
      v[2] = f2bf(acc[a][2]); v[3] = f2bf(acc[a][3]);
      *(us4v*)&gxTb[(size_t)(ty * 4 + a) * N + n0 + tx * 4] = v;
    }
  }

  // xT tile: rows n (spatial), cols c — transpose out of xs
  {
    const int nloc = tid >> 2, cs = (tid & 3) * 16;
    us8v u0, u1;
#pragma unroll
    for (int j = 0; j < 8; ++j) u0[j] = f2bf(xs[(cs + j) * LS + nloc]);
#pragma unroll
    for (int j = 0; j < 8; ++j) u1[j] = f2bf(xs[(cs + 8 + j) * LS + nloc]);
    unsigned short* xTb = xT + (size_t)b * N * 64;
    *(us8v*)&xTb[(size_t)(n0 + nloc) * 64 + cs] = u0;
    *(us8v*)&xTb[(size_t)(n0 + nloc) * 64 + cs + 8] = u1;
  }
}

// v6 relation: v4's proven loop (plain dwordx4 score stores — NT store reverted:
// L2 write-merging of the 64B row segments is load-bearing for the 328 MB
// score stream; bypassing it cost ~35 µs in v5).
__global__ __launch_bounds__(256, 4) void relation_main(
    const unsigned short* __restrict__ xT, const unsigned short* __restrict__ gxT,
    float* __restrict__ score, float* __restrict__ emb_p) {
  __shared__ alignas(16) unsigned short xmT[64 * LSB];  // [m][c]
  __shared__ alignas(16) unsigned short gxt[64 * LSB];  // [i][m]
  __shared__ alignas(16) unsigned short sc[64 * LSB];   // [n][m], wave-private bands

  const int tid = threadIdx.x;
  const int w = tid >> 6, lane = tid & 63;
  const int l15 = lane & 15, quad = lane >> 4;

  const int bIdx = blockIdx.x / (NT * MSPLIT);
  const int rest = blockIdx.x % (NT * MSPLIT);
  const int nt = rest / MSPLIT;
  const int ms = rest % MSPLIT;
  const int n0 = nt * 64;
  const int nw = n0 + 16 * w;  // this wave's first n-row

  const unsigned short* xTb = xT + (size_t)bIdx * N * 64;
  const unsigned short* gxTb = gxT + (size_t)bIdx * 64 * N;
  float* scoreb = score + (size_t)bIdx * N * N;

  // loop-invariant B-operand frags (Xn, this wave's 16 n-rows), direct from global
  short8 bn0 = *(const short8*)&xTb[(size_t)(nw + l15) * 64 + quad * 8];
  short8 bn1 = *(const short8*)&xTb[(size_t)(nw + l15) * 64 + 32 + quad * 8];

  const int srow = tid >> 3, sco = (tid & 7) * 8;  // staging row/col (rows srow, srow+32)

  // prefetch m-tile 0 into registers
  const int mbase = ms * MT_PER * 64;
  us8v xm0 = *(const us8v*)&xTb[(size_t)(mbase + srow) * 64 + sco];
  us8v xm1 = *(const us8v*)&xTb[(size_t)(mbase + srow + 32) * 64 + sco];
  us8v gx0 = *(const us8v*)&gxTb[(size_t)srow * N + mbase + sco];
  us8v gx1 = *(const us8v*)&gxTb[(size_t)(srow + 32) * N + mbase + sco];

  f32x4 e[4];  // emb acc: D[i][n], [isub]; lane: col n = l15, rows i = 16*is+quad*4+r
  const f32x4 zero = {0.f, 0.f, 0.f, 0.f};
#pragma unroll
  for (int is = 0; is < 4; ++is) e[is] = zero;

  for (int j = 0; j < MT_PER; ++j) {
    const int mj = (ms * MT_PER + j) * 64;

    // WAR boundary: own LDS reads drained, then all waves aligned. No vmcnt drain.
    asm volatile("s_waitcnt lgkmcnt(0)" ::: "memory");
    __builtin_amdgcn_s_barrier();
    *(us8v*)&xmT[srow * LSB + sco] = xm0;
    *(us8v*)&xmT[(srow + 32) * LSB + sco] = xm1;
    *(us8v*)&gxt[srow * LSB + sco] = gx0;
    *(us8v*)&gxt[(srow + 32) * LSB + sco] = gx1;
    // RAW boundary: staging writes landed, then aligned; reads below stay below.
    asm volatile("s_waitcnt lgkmcnt(0)" ::: "memory");
    __builtin_amdgcn_s_barrier();
    __builtin_amdgcn_sched_barrier(0);

    if (j + 1 < MT_PER) {  // prefetch next tile: drains under this iter's compute
      const int m1 = mj + 64;
      xm0 = *(const us8v*)&xTb[(size_t)(m1 + srow) * 64 + sco];
      xm1 = *(const us8v*)&xTb[(size_t)(m1 + srow + 32) * 64 + sco];
      gx0 = *(const us8v*)&gxTb[(size_t)srow * N + m1 + sco];
      gx1 = *(const us8v*)&gxTb[(size_t)(srow + 32) * N + m1 + sco];
    }

    // aff = mfma(Xm, Xn): D[m][n]; sigmoid; fp32 score (dwordx4); bf16 P -> sc.
#pragma unroll
    for (int msub = 0; msub < 4; ++msub) {
      short8 am0 = *(const short8*)&xmT[(16 * msub + l15) * LSB + quad * 8];
      short8 am1 = *(const short8*)&xmT[(16 * msub + l15) * LSB + 32 + quad * 8];
      f32x4 d = __builtin_amdgcn_mfma_f32_16x16x32_bf16(am0, bn0, zero, 0, 0, 0);
      d = __builtin_amdgcn_mfma_f32_16x16x32_bf16(am1, bn1, d, 0, 0, 0);
      f32x4 sg; us4v sb;
#pragma unroll
      for (int r = 0; r < 4; ++r) {
        float t = __builtin_amdgcn_exp2f(-1.442695041f * d[r]);
        sg[r] = __builtin_amdgcn_rcpf(1.f + t);
        sb[r] = f2bf(sg[r]);
      }
      *(f32x4*)&scoreb[(size_t)(nw + l15) * N + mj + 16 * msub + quad * 4] = sg;
      *(us4v*)&sc[(16 * w + l15) * LSB + 16 * msub + quad * 4] = sb;
    }

    // emb += mfma(G, P): D[i][n]. P from wave-private sc band (same-wave RAW:
    // compiler inserts lgkmcnt). G from staged LDS.
    short8 p0 = *(const short8*)&sc[(16 * w + l15) * LSB + quad * 8];
    short8 p1 = *(const short8*)&sc[(16 * w + l15) * LSB + 32 + quad * 8];
#pragma unroll
    for (int is = 0; is < 4; ++is) {
      short8 g0 = *(const short8*)&gxt[(16 * is + l15) * LSB + quad * 8];
      short8 g1 = *(const short8*)&gxt[(16 * is + l15) * LSB + 32 + quad * 8];
      e[is] = __builtin_amdgcn_mfma_f32_16x16x32_bf16(g0, p0, e[is], 0, 0, 0);
      e[is] = __builtin_amdgcn_mfma_f32_16x16x32_bf16(g1, p1, e[is], 0, 0, 0);
    }
  }

  // emb partial store (fp32, dwordx4): emb_p[ms][b][n][i]
  float* ep = emb_p + ((size_t)ms * B + bIdx) * (size_t)N * 64;
#pragma unroll
  for (int is = 0; is < 4; ++is)
    *(f32x4*)&ep[(size_t)(nw + l15) * 64 + 16 * is + quad * 4] = e[is];
}

// y[b,o,n] = sum_i w_w[o,i] * emb[b,n,i] + w_b[o]; emb = sum of MSPLIT partials.
// Fused GroupNorm partial stats: each thread's 16 acc values all belong to
// group g = tid>>5. 32-lane shuffle reduce -> 2 atomicAdds per half-wave.
__global__ __launch_bounds__(256) void y_kernel(
    const float* __restrict__ emb_p, const float* __restrict__ w_w,
    const float* __restrict__ w_b, float* __restrict__ y,
    float* __restrict__ stats_acc) {
  __shared__ float embT[64 * LS];  // [i][n]
  __shared__ float wt[64 * LS];    // [i][o]
  const int b = blockIdx.x / NT;
  const int n0 = (blockIdx.x % NT) * 64;
  const int tid = threadIdx.x;
  const int col = tid & 63, row4 = tid >> 6;
  const int ty = tid >> 4, tx = tid & 15;
#pragma unroll
  for (int it = 0; it < 16; ++it) {
    int r = row4 + it * 4;
    wt[col * LS + r] = w_w[r * 64 + col];
    float v = 0.f;
#pragma unroll
    for (int msv = 0; msv < MSPLIT; ++msv)
      v += emb_p[((size_t)msv * B + b) * N * C + (size_t)(n0 + r) * C + col];
    embT[col * LS + r] = v;
  }
  __syncthreads();
  float acc[4][4];
#pragma unroll
  for (int a = 0; a < 4; ++a) {
    float wbv = w_b[ty * 4 + a];
    acc[a][0] = wbv; acc[a][1] = wbv; acc[a][2] = wbv; acc[a][3] = wbv;
  }
#pragma unroll 8
  for (int i = 0; i < 64; ++i) {
    const f32x4 w4 = *(const f32x4*)&wt[i * LS + ty * 4];
    const f32x4 e4 = *(const f32x4*)&embT[i * LS + tx * 4];
#pragma unroll
    for (int a = 0; a < 4; ++a) {
      acc[a][0] += w4[a] * e4[0]; acc[a][1] += w4[a] * e4[1];
      acc[a][2] += w4[a] * e4[2]; acc[a][3] += w4[a] * e4[3];
    }
  }
  float* yb = y + (size_t)b * C * N;
  float s = 0.f, q = 0.f;
#pragma unroll
  for (int a = 0; a < 4; ++a) {
    f32x4 v = {acc[a][0], acc[a][1], acc[a][2], acc[a][3]};
    *(f32x4*)&yb[(size_t)(ty * 4 + a) * N + n0 + tx * 4] = v;
    s += v[0] + v[1] + v[2] + v[3];
    q += v[0] * v[0] + v[1] * v[1] + v[2] * v[2] + v[3] * v[3];
  }
#pragma unroll
  for (int off = 16; off > 0; off >>= 1) {
    s += __shfl_down(s, off, 32);
    q += __shfl_down(q, off, 32);
  }
  if ((tid & 31) == 0) {
    const int g = tid >> 5;  // group of this half-wave's 8 channels
    atomicAdd(&stats_acc[(b * 8 + g) * 2 + 0], s);
    atomicAdd(&stats_acc[(b * 8 + g) * 2 + 1], q);
  }
}

// finalize folded in — mean/rstd from the (S,Q) accumulators (L2-hot broadcasts).
__global__ __launch_bounds__(256) void norm_kernel(
    const float* __restrict__ y, const float* __restrict__ stats_acc,
    const float* __restrict__ gn_w, const float* __restrict__ gn_b,
    float* __restrict__ out) {
  const int idx = blockIdx.x * 256 + threadIdx.x;
  const int e0 = idx * 4;
  const int b = e0 / (C * N);
  const int c = (e0 / N) & 63;
  const int g = c >> 3;
  const float S = stats_acc[(b * 8 + g) * 2 + 0];
  const float Q = stats_acc[(b * 8 + g) * 2 + 1];
  const float inv = 1.f / (float)(8 * N);
  const float mean = S * inv;
  const float var = Q * inv - mean * mean;
  const float rstd = rsqrtf(var + EPS);
  const float w = gn_w[c] * rstd;
  const float bb = gn_b[c] - mean * w;
  f32x4 v = *(const f32x4*)&y[e0];
  v[0] = v[0] * w + bb; v[1] = v[1] * w + bb;
  v[2] = v[2] * w + bb; v[3] = v[3] * w + bb;
  *(f32x4*)&out[e0] = v;
}

extern "C" void kernel_launch(void* const* d_in, const int* in_sizes, int n_in,
                              void* d_out, int out_size, void* d_ws, size_t ws_size,
                              hipStream_t stream) {
  const float* x    = (const float*)d_in[0];
  const float* g_w  = (const float*)d_in[1];
  const float* g_b  = (const float*)d_in[2];
  const float* w_w  = (const float*)d_in[3];
  const float* w_b  = (const float*)d_in[4];
  const float* gn_w = (const float*)d_in[5];
  const float* gn_b = (const float*)d_in[6];
  (void)in_sizes; (void)n_in; (void)out_size; (void)ws_size;

  float* out   = (float*)d_out;
  float* score = out + (size_t)B * C * N;

  float* ws    = (float*)d_ws;
  float* emb_p = ws;                                       // MSPLIT*B*N*C fp32
  float* y     = emb_p + (size_t)MSPLIT * B * N * C;       // B*C*N fp32
  float* stats = y + (size_t)B * C * N;                    // 32 fp32 (S,Q accum)
  unsigned short* xT  = (unsigned short*)(stats + 32);     // B*N*64 bf16
  unsigned short* gxT = xT + (size_t)B * N * 64;           // B*64*N bf16

  hipLaunchKernelGGL(xprep_kernel, dim3(B * NT), dim3(256), 0, stream,
                     x, g_w, g_b, xT, gxT, stats);
  hipLaunchKernelGGL(relation_main, dim3(B * NT * MSPLIT), dim3(256), 0, stream,
                     xT, gxT, score, emb_p);
  hipLaunchKernelGGL(y_kernel, dim3(B * NT), dim3(256), 0, stream,
                     emb_p, w_w, w_b, y, stats);
  hipLaunchKernelGGL(norm_kernel, dim3((B * C * N) / 1024), dim3(256), 0, stream,
                     y, stats, gn_w, gn_b, out);
}